// Round 6
// baseline (509.999 us; speedup 1.0000x reference)
//
#include <hip/hip_runtime.h>

// ---------------------------------------------------------------------------
// DNANet round 5: fused attention+projection layers.
// N=50000 nodes, E=600000 edges (+N self loops), HID=64, HEADS=4, d=16.
//
// Planes: PL[node][l][dim] u32 = bf16(k_l) | bf16(v_l * dinv[node])<<16
//         (768 B per node, chunk l = 256 B coalesced)
// V0 plane: u16 = bf16(v_0 * dinv)   (128 B/node, for the L=1 layer)
//
// Layer t attn kernel (1024 thr = 16 dst nodes/block, Wq/Wk/Wv in 48KB LDS):
//   gather+softmax over L=t slices -> row (regs) -> epilogue projects row
//   into q + plane chunk t (or W_out for t=3). Slices never hit memory.
// ---------------------------------------------------------------------------

__device__ inline unsigned short bf16_rne(float f) {
    unsigned int u = __float_as_uint(f);
    unsigned int r = u + 0x7FFFu + ((u >> 16) & 1u);
    return (unsigned short)(r >> 16);
}

__global__ __launch_bounds__(256) void hist_dst_k(const int* __restrict__ dst,
                                                  int* __restrict__ cnt, int E) {
    int e = blockIdx.x * 256 + threadIdx.x;
    if (e < E) atomicAdd(&cnt[dst[e]], 1);
}

// Exclusive scan of (cnt[i]+1), stage 1 (1024-elem chunks); also emits dinv.
__global__ __launch_bounds__(256) void scan1_k(const int* __restrict__ cnt,
                                               int* __restrict__ excl,
                                               int* __restrict__ aux,
                                               float* __restrict__ dinv, int N) {
    __shared__ int wtot[4];
    int b = blockIdx.x, t = threadIdx.x;
    int lane = t & 63, w = t >> 6;
    int base = b * 1024 + t * 4;
    int v0 = (base + 0 < N) ? cnt[base + 0] + 1 : 0;
    int v1 = (base + 1 < N) ? cnt[base + 1] + 1 : 0;
    int v2 = (base + 2 < N) ? cnt[base + 2] + 1 : 0;
    int v3 = (base + 3 < N) ? cnt[base + 3] + 1 : 0;
    if (base + 0 < N) dinv[base + 0] = rsqrtf((float)v0);
    if (base + 1 < N) dinv[base + 1] = rsqrtf((float)v1);
    if (base + 2 < N) dinv[base + 2] = rsqrtf((float)v2);
    if (base + 3 < N) dinv[base + 3] = rsqrtf((float)v3);
    int s = v0 + v1 + v2 + v3;
    int incl = s;
#pragma unroll
    for (int off = 1; off < 64; off <<= 1) {
        int u = __shfl_up(incl, off);
        if (lane >= off) incl += u;
    }
    if (lane == 63) wtot[w] = incl;
    __syncthreads();
    int wb = 0;
#pragma unroll
    for (int j = 0; j < 4; ++j) if (j < w) wb += wtot[j];
    int ex = wb + incl - s;
    if (base + 0 < N) excl[base + 0] = ex;
    if (base + 1 < N) excl[base + 1] = ex + v0;
    if (base + 2 < N) excl[base + 2] = ex + v0 + v1;
    if (base + 3 < N) excl[base + 3] = ex + v0 + v1 + v2;
    if (t == 0) aux[b] = wtot[0] + wtot[1] + wtot[2] + wtot[3];
}

__global__ __launch_bounds__(64) void scan_aux_k(int* __restrict__ aux, int nb,
                                                 int* __restrict__ total) {
    int lane = threadIdx.x;
    int v = (lane < nb) ? aux[lane] : 0;
    int incl = v;
#pragma unroll
    for (int off = 1; off < 64; off <<= 1) {
        int u = __shfl_up(incl, off);
        if (lane >= off) incl += u;
    }
    if (lane < nb) aux[lane] = incl - v;
    if (lane == 63) total[0] = incl;
}

__global__ __launch_bounds__(256) void scan_add_k(int* __restrict__ offs,
                                                  const int* __restrict__ aux,
                                                  int* __restrict__ cursor, int N) {
    int i = blockIdx.x * 256 + threadIdx.x;
    if (i < N) {
        int o = offs[i] + aux[i >> 10];
        offs[i] = o;
        cursor[i] = o;
    }
}

__global__ __launch_bounds__(256) void scatter_dst_k(const int* __restrict__ src,
                                                     const int* __restrict__ dst,
                                                     int* __restrict__ cursor,
                                                     int* __restrict__ src_sorted,
                                                     int E, int N) {
    int e = blockIdx.x * 256 + threadIdx.x;
    int M = E + N;
    if (e >= M) return;
    int s, d;
    if (e < E) { s = src[e]; d = dst[e]; }
    else       { s = d = e - E; }
    int pos = atomicAdd(&cursor[d], 1);
    src_sorted[pos] = s;
}

// h[N x 64] = x[N x 128] @ W[128 x 64] + b ; 16 rows/block (4 rows/thread).
__global__ __launch_bounds__(256) void lin128_64_k(const float* __restrict__ x,
                                                   const float* __restrict__ W,
                                                   const float* __restrict__ b,
                                                   float* __restrict__ y, int N) {
    __shared__ float sW[128 * 64];
    __shared__ float sb[64];
    for (int i = threadIdx.x; i < 128 * 64; i += 256) sW[i] = W[i];
    if (threadIdx.x < 64) sb[threadIdx.x] = b[threadIdx.x];
    __syncthreads();
    int w = threadIdx.x >> 6, c = threadIdx.x & 63;
    int r0 = blockIdx.x * 16 + w * 4;
    if (r0 >= N) return;
    const float* xr[4];
#pragma unroll
    for (int j = 0; j < 4; ++j) {
        int r = r0 + j; if (r > N - 1) r = N - 1;
        xr[j] = x + (size_t)r * 128;
    }
    float acc[4];
#pragma unroll
    for (int j = 0; j < 4; ++j) acc[j] = sb[c];
    for (int k = 0; k < 128; ++k) {
        float wv = sW[k * 64 + c];
#pragma unroll
        for (int j = 0; j < 4; ++j) acc[j] = fmaf(xr[j][k], wv, acc[j]);
    }
#pragma unroll
    for (int j = 0; j < 4; ++j) {
        int r = r0 + j;
        if (r < N) y[(size_t)r * 64 + c] = acc[j];
    }
}

// Slice-0 pack: read h rows, project to q / plane chunk 0 / V0.
// 1024 threads = 16 rows/block; Wq/Wk/Wv in LDS.
__global__ __launch_bounds__(1024) void qkv_pack0_k(const float* __restrict__ h,
                                                    const float* __restrict__ Wq, const float* __restrict__ bq,
                                                    const float* __restrict__ Wk, const float* __restrict__ bk,
                                                    const float* __restrict__ Wv, const float* __restrict__ bv,
                                                    const float* __restrict__ dinv,
                                                    float* __restrict__ q,
                                                    unsigned int* __restrict__ PL,
                                                    unsigned short* __restrict__ V0,
                                                    int N) {
    __shared__ float sW[3 * 64 * 64];
    __shared__ float rowS[16][64];
    int tid = threadIdx.x;
    for (int i = tid; i < 4096; i += 1024) {
        sW[i] = Wq[i]; sW[4096 + i] = Wk[i]; sW[8192 + i] = Wv[i];
    }
    __syncthreads();
    int w = tid >> 6, lane = tid & 63;
    int r = blockIdx.x * 16 + w;
    if (r >= N) return;
    rowS[w][lane] = h[(size_t)r * 64 + lane];
    float dr = dinv[r];
    float aq = bq[lane], ak = bk[lane], av = bv[lane];
#pragma unroll 8
    for (int k = 0; k < 64; ++k) {
        float xk = rowS[w][k];
        aq = fmaf(xk, sW[k * 64 + lane], aq);
        ak = fmaf(xk, sW[4096 + k * 64 + lane], ak);
        av = fmaf(xk, sW[8192 + k * 64 + lane], av);
    }
    q[(size_t)r * 64 + lane] = aq;
    unsigned short vb = bf16_rne(av * dr);
    PL[(size_t)r * 192 + lane] = (unsigned int)bf16_rne(ak) | ((unsigned int)vb << 16);
    V0[(size_t)r * 64 + lane] = vb;
}

// Fused attention layer t (L = t slices) + projection epilogue.
// One dst node per wave, 16 waves/block. EMIT_OUT: apply W_out instead of QKV.
template <int L, bool EMIT_OUT>
__global__ __launch_bounds__(1024) void attn_fused_k(const int* __restrict__ offs,
                                                     const int* __restrict__ src_sorted,
                                                     const float* __restrict__ dinv,
                                                     float* __restrict__ q,          // in/out (slot-private per wave)
                                                     unsigned int* __restrict__ PL,  // read chunks [0,L), write chunk L
                                                     const unsigned short* __restrict__ V0,
                                                     const float* __restrict__ WA, const float* __restrict__ bA, // Wq|W_out
                                                     const float* __restrict__ Wk, const float* __restrict__ bk,
                                                     const float* __restrict__ Wv, const float* __restrict__ bv,
                                                     float* __restrict__ out, int N) {
    constexpr int SWSZ = EMIT_OUT ? (64 * 16) : (3 * 64 * 64);
    __shared__ float sW[SWSZ];
    __shared__ float rowS[16][64];
    int tid = threadIdx.x;
    if (EMIT_OUT) {
        for (int i = tid; i < 64 * 16; i += 1024) sW[i] = WA[i];
    } else {
        for (int i = tid; i < 4096; i += 1024) {
            sW[i] = WA[i]; sW[4096 + i] = Wk[i]; sW[8192 + i] = Wv[i];
        }
    }
    __syncthreads();
    int w = tid >> 6, lane = tid & 63;
    int d = blockIdx.x * 16 + w;
    if (d >= N) return;

    int beg = offs[d], end = offs[d + 1];
    float qv = (L > 1) ? q[(size_t)d * 64 + lane] : 0.0f;
    float acc = 0.0f;

    for (int base = beg; base < end; base += 64) {
        int m = end - base;
        if (m > 64) m = 64;
        int sid = (base + lane < end) ? src_sorted[base + lane] : 0;
#pragma unroll 4
        for (int i = 0; i < m; ++i) {
            int s = __shfl(sid, i);
            if (L == 1) {
                acc += __uint_as_float((unsigned int)V0[(size_t)s * 64 + lane] << 16);
            } else if (L == 2) {
                const unsigned int* p = PL + (size_t)s * 192;
                unsigned int u0 = p[lane];
                unsigned int u1 = p[64 + lane];
                float k0 = __uint_as_float((u0 & 0xFFFFu) << 16);
                float v0 = __uint_as_float(u0 & 0xFFFF0000u);
                float k1 = __uint_as_float((u1 & 0xFFFFu) << 16);
                float v1 = __uint_as_float(u1 & 0xFFFF0000u);
                float p0 = qv * k0;
                float p1 = qv * k1;
#pragma unroll
                for (int mk = 8; mk >= 1; mk >>= 1) {
                    p0 += __shfl_xor(p0, mk);
                    p1 += __shfl_xor(p1, mk);
                }
                float e  = __expf((p1 - p0) * 0.25f);     // / sqrt(16)
                float w0 = __builtin_amdgcn_rcpf(1.0f + e);
                float w1 = 1.0f - w0;
                acc = fmaf(w0, v0, acc);
                acc = fmaf(w1, v1, acc);
            } else {
                const unsigned int* p = PL + (size_t)s * 192;
                unsigned int u0 = p[lane];
                unsigned int u1 = p[64 + lane];
                unsigned int u2 = p[128 + lane];
                float k0 = __uint_as_float((u0 & 0xFFFFu) << 16);
                float v0 = __uint_as_float(u0 & 0xFFFF0000u);
                float k1 = __uint_as_float((u1 & 0xFFFFu) << 16);
                float v1 = __uint_as_float(u1 & 0xFFFF0000u);
                float k2 = __uint_as_float((u2 & 0xFFFFu) << 16);
                float v2 = __uint_as_float(u2 & 0xFFFF0000u);
                float p0 = qv * k0;
                float p1 = qv * k1;
                float p2 = qv * k2;
#pragma unroll
                for (int mk = 8; mk >= 1; mk >>= 1) {
                    p0 += __shfl_xor(p0, mk);
                    p1 += __shfl_xor(p1, mk);
                    p2 += __shfl_xor(p2, mk);
                }
                float s0 = p0 * 0.25f, s1 = p1 * 0.25f, s2 = p2 * 0.25f;
                float mx = fmaxf(fmaxf(s0, s1), s2);
                float w0 = __expf(s0 - mx);
                float w1 = __expf(s1 - mx);
                float w2 = __expf(s2 - mx);
                float inv = __builtin_amdgcn_rcpf(w0 + w1 + w2);
                float msg = w0 * v0;
                msg = fmaf(w1, v1, msg);
                msg = fmaf(w2, v2, msg);
                acc = fmaf(msg, inv, acc);
            }
        }
    }

    float dr = dinv[d];
    float rv = acc * dr;                 // next slice value (fp32, register-only)
    rowS[w][lane] = rv;

    if (EMIT_OUT) {
        int co = lane & 15;
        float ao = bA[co];
#pragma unroll 8
        for (int k = 0; k < 64; ++k) ao = fmaf(rowS[w][k], sW[k * 16 + co], ao);
        if (lane < 16) out[(size_t)d * 16 + co] = ao;
    } else {
        float aq = bA[lane], ak = bk[lane], av = bv[lane];
#pragma unroll 8
        for (int k = 0; k < 64; ++k) {
            float xk = rowS[w][k];
            aq = fmaf(xk, sW[k * 64 + lane], aq);
            ak = fmaf(xk, sW[4096 + k * 64 + lane], ak);
            av = fmaf(xk, sW[8192 + k * 64 + lane], av);
        }
        q[(size_t)d * 64 + lane] = aq;
        PL[(size_t)d * 192 + L * 64 + lane] =
            (unsigned int)bf16_rne(ak) | ((unsigned int)bf16_rne(av * dr) << 16);
    }
}

extern "C" void kernel_launch(void* const* d_in, const int* in_sizes, int n_in,
                              void* d_out, int out_size, void* d_ws, size_t ws_size,
                              hipStream_t stream) {
    const float* x     = (const float*)d_in[0];
    const int*   ei    = (const int*)d_in[1];
    const float* W_lin = (const float*)d_in[2];
    const float* b_lin = (const float*)d_in[3];
    const float* Wq    = (const float*)d_in[4];
    const float* bq    = (const float*)d_in[5];
    const float* Wk    = (const float*)d_in[6];
    const float* bk    = (const float*)d_in[7];
    const float* Wv    = (const float*)d_in[8];
    const float* bv    = (const float*)d_in[9];
    const float* W_out = (const float*)d_in[10];
    const float* b_out = (const float*)d_in[11];
    float* out = (float*)d_out;

    const int N = in_sizes[0] / 128;
    const int E = in_sizes[1] / 2;
    const int M = E + N;
    const int* srcp = ei;
    const int* dstp = ei + E;

    char* wsb = (char*)d_ws;
    float*          dinv       = (float*)wsb;           wsb += (size_t)N * sizeof(float);
    int*            cnt        = (int*)wsb;             wsb += (size_t)N * sizeof(int);
    int*            offs       = (int*)wsb;             wsb += (size_t)(N + 1) * sizeof(int);
    int*            cursor     = (int*)wsb;             wsb += (size_t)N * sizeof(int);
    int*            aux        = (int*)wsb;             wsb += 64 * sizeof(int);
    int*            src_sorted = (int*)wsb;             wsb += (size_t)M * sizeof(int);
    float*          qb         = (float*)wsb;           wsb += (size_t)N * 64 * sizeof(float);
    unsigned int*   PL         = (unsigned int*)wsb;    wsb += (size_t)N * 192 * sizeof(unsigned int);
    unsigned short* V0p        = (unsigned short*)wsb;  wsb += (size_t)N * 64 * sizeof(unsigned short);
    float*          hA         = (float*)wsb;

    const int gN   = (N + 255) / 256;
    const int gE   = (E + 255) / 256;
    const int gM   = (M + 255) / 256;
    const int g16  = (N + 15) / 16;        // 16 rows per block
    const int nb   = (N + 1023) / 1024;    // scan chunks (<= 64 for N <= 65536)

    // degree -> dinv + dst-CSR
    hipMemsetAsync(cnt, 0, (size_t)N * sizeof(int), stream);
    hist_dst_k<<<gE, 256, 0, stream>>>(dstp, cnt, E);
    scan1_k<<<nb, 256, 0, stream>>>(cnt, offs, aux, dinv, N);
    scan_aux_k<<<1, 64, 0, stream>>>(aux, nb, offs + N);
    scan_add_k<<<gN, 256, 0, stream>>>(offs, aux, cursor, N);
    scatter_dst_k<<<gM, 256, 0, stream>>>(srcp, dstp, cursor, src_sorted, E, N);

    // slice 0: h = x@W_lin + b, then project/pack
    lin128_64_k<<<g16, 256, 0, stream>>>(x, W_lin, b_lin, hA, N);
    qkv_pack0_k<<<g16, 1024, 0, stream>>>(hA, Wq, bq, Wk, bk, Wv, bv, dinv,
                                          qb, PL, V0p, N);

    // layers 1..3 (fused attn + projection)
    attn_fused_k<1, false><<<g16, 1024, 0, stream>>>(offs, src_sorted, dinv, qb, PL, V0p,
                                                     Wq, bq, Wk, bk, Wv, bv, out, N);
    attn_fused_k<2, false><<<g16, 1024, 0, stream>>>(offs, src_sorted, dinv, qb, PL, V0p,
                                                     Wq, bq, Wk, bk, Wv, bv, out, N);
    attn_fused_k<3, true><<<g16, 1024, 0, stream>>>(offs, src_sorted, dinv, qb, PL, V0p,
                                                    W_out, b_out, Wk, bk, Wv, bv, out, N);
}